// Round 11
// baseline (973.758 us; speedup 1.0000x reference)
//
#include <hip/hip_runtime.h>
#include <hip/hip_bf16.h>
#include <hip/hip_fp16.h>

// GCN: h1 = relu(gcn(x,W1,b1)); h2 = relu(gcn(h1,W2,b2));
// pooled = segment_sum(h2, batch); out = sigmoid(pooled@Wc + bc)
// R13/R14 NEUTRAL. R15-17 FAILED: latency-starved bin-sweep; TLP>>locality.
//   BANKED: atomicAdd(float*) = ~200cyc CAS; use unsafeAtomicAdd.
// R18 NEUTRAL. R19: nt hints BACKFIRE (evict-early); fp16 H GOOD. R20 WIN
//   (545->510): LDS tile-sort bin_edges. R21 (509): 512-thr bins -19us tail;
//   agg split cost +17 (less TLP/dispatch) — merged back. Top-5 is instances
//   of the SLOWEST kernel across iters; splitting can't surface #2.
// R22: tail ledger says bin_edges+bin_sort ~145us vs ~25 ideal (LDS-sort
//   barrier/atomic overhead at 2 blocks/CU). With EXACT CSR, mean run =
//   32edges x 8B = 256B ~ 1 line -> direct global scatter is NOT write-
//   amplified. Replace both with: k_hist (deg/wsum atomics) -> 3 micro-scan
//   kernels -> k_scatter (cursor atomic, 8B writes into 256B runs). Zero
//   LDS, zero barriers, full TLP. Merge wt_preps. agg full-range.
//   Pred: agg ~115x2/381MB; pre ~50; total 509 -> 415-455; absmax same.
//   Falsif: >=490 => bins weren't the tail -> fuse/accept; scatter >=60
//   => cursor serialization -> hybrid.

#define FEAT 128
#define OUTC 64
#define CHUNK 2048     // nodes per scan chunk

typedef _Float16 half8 __attribute__((ext_vector_type(8)));
typedef float    f32x4 __attribute__((ext_vector_type(4)));
typedef int      iv4  __attribute__((ext_vector_type(4)));

// ---- k_hist: per-target degree + weighted degree (global atomics) ----------
__global__ __launch_bounds__(256) void k_hist(const int* __restrict__ ei,
                                              const float* __restrict__ ew,
                                              int* __restrict__ deg,
                                              float* __restrict__ wsum, int E) {
    int stride = gridDim.x * 256;
    for (int e = blockIdx.x * 256 + threadIdx.x; e < E; e += stride) {
        int col = ei[E + e];
        atomicAdd(&deg[col], 1);
        unsafeAtomicAdd(&wsum[col], ew[e]);
    }
}

// ---- k_chunksum: per-chunk degree totals -----------------------------------
__global__ __launch_bounds__(512) void k_chunksum(const int* __restrict__ deg,
                                                  int* __restrict__ chunkSum, int N) {
    __shared__ int ts[512];
    int tid = threadIdx.x;
    int base = blockIdx.x * CHUNK + tid * 4;
    int s = 0;
    #pragma unroll
    for (int j = 0; j < 4; ++j)
        if (base + j < N) s += deg[base + j];
    ts[tid] = s;
    __syncthreads();
    for (int off = 256; off > 0; off >>= 1) {
        if (tid < off) ts[tid] += ts[tid + off];
        __syncthreads();
    }
    if (tid == 0) chunkSum[blockIdx.x] = ts[0];
}

// ---- k_scanchunks: exclusive scan of chunk sums (1 block) ------------------
__global__ __launch_bounds__(64) void k_scanchunks(const int* __restrict__ chunkSum,
                                                   int* __restrict__ chunkBase, int NC) {
    __shared__ int ts[64];
    int tid = threadIdx.x;
    int v = (tid < NC) ? chunkSum[tid] : 0;
    ts[tid] = v;
    __syncthreads();
    for (int off = 1; off < 64; off <<= 1) {
        int a = (tid >= off) ? ts[tid - off] : 0;
        __syncthreads();
        ts[tid] += a;
        __syncthreads();
    }
    if (tid < NC) chunkBase[tid] = ts[tid] - v;
}

// ---- k_offs: per-node CSR offsets + cursor init + dinv ---------------------
__global__ __launch_bounds__(512) void k_offs(const int* __restrict__ deg,
                                              const float* __restrict__ wsum,
                                              const int* __restrict__ chunkBase,
                                              int* __restrict__ offs,
                                              int* __restrict__ cur,
                                              float* __restrict__ dinv, int N) {
    __shared__ int ts[512];
    int tid = threadIdx.x;
    int base = blockIdx.x * CHUNK + tid * 4;
    int d[4] = {0, 0, 0, 0};
    #pragma unroll
    for (int j = 0; j < 4; ++j)
        if (base + j < N) d[j] = deg[base + j];
    int s = d[0] + d[1] + d[2] + d[3];
    ts[tid] = s;
    __syncthreads();
    for (int off = 1; off < 512; off <<= 1) {
        int a = (tid >= off) ? ts[tid - off] : 0;
        __syncthreads();
        ts[tid] += a;
        __syncthreads();
    }
    int o = chunkBase[blockIdx.x] + ts[tid] - s;
    #pragma unroll
    for (int j = 0; j < 4; ++j) {
        int n = base + j;
        if (n < N) {
            offs[n] = o;
            cur[n]  = o;
            dinv[n] = rsqrtf(1.0f + wsum[n]);
            o += d[j];
        }
    }
}

// ---- k_scatter: direct CSR scatter (8B writes into ~256B runs) -------------
__global__ __launch_bounds__(256) void k_scatter(const int* __restrict__ ei,
                                                 const float* __restrict__ ew,
                                                 int* __restrict__ cur,
                                                 int2* __restrict__ elist, int E) {
    int stride = gridDim.x * 256;
    for (int e = blockIdx.x * 256 + threadIdx.x; e < E; e += stride) {
        int col = ei[E + e];
        int row = ei[e];
        unsigned short hs = __half_as_ushort(__float2half(ew[e]));
        int pos = atomicAdd(&cur[col], 1);
        elist[pos] = make_int2(row, (int)hs | ((int)hs << 16));
    }
}

// ---- one-time padded W^T fp16 prep for BOTH layers (row stride LDW) --------
#define LDW 136
__global__ void wt_prep(const float* __restrict__ W1, const float* __restrict__ W2,
                        _Float16* __restrict__ Wt1, _Float16* __restrict__ Wt2) {
    int i = blockIdx.x * 256 + threadIdx.x;   // i < 32768
    int sel = i >> 14;
    int r = i & 16383;
    int n = r >> 7, k = r & 127;
    const float* W = sel ? W2 : W1;
    _Float16* Wt = sel ? Wt2 : Wt1;
    Wt[(size_t)n * LDW + k] = (_Float16)W[(size_t)k * FEAT + n];
}

// ---- Y(fp16) = dinv[:,None]*(X @ W) via MFMA; TIn = float or __half --------
template<typename TIn>
__global__ __launch_bounds__(256) void gemm_mfma(const TIn* __restrict__ X,
                                                 const _Float16* __restrict__ Wt,
                                                 const float* __restrict__ dinv,
                                                 __half* __restrict__ Y, int N) {
    __shared__ _Float16 sWt[FEAT * LDW];   // 34816 B
    int tid  = threadIdx.x;
    int row0 = blockIdx.x * 128;
    {
        const int4* src = (const int4*)Wt;
        int4* dst = (int4*)sWt;
        for (int i = tid; i < (FEAT * LDW) / 8; i += 256) dst[i] = src[i];
    }
    __syncthreads();

    int wave = tid >> 6;
    int lane = tid & 63;
    int m    = lane & 15;
    int quad = lane >> 4;

    f32x4 acc[2][8];
    #pragma unroll
    for (int rt = 0; rt < 2; ++rt)
        #pragma unroll
        for (int ct = 0; ct < 8; ++ct)
            acc[rt][ct] = (f32x4){0.f, 0.f, 0.f, 0.f};

    int rowA[2];
    rowA[0] = min(row0 + wave * 32 + m, N - 1);
    rowA[1] = min(row0 + wave * 32 + 16 + m, N - 1);

    #pragma unroll
    for (int kt = 0; kt < 4; ++kt) {
        int k0 = kt * 32;
        half8 a[2];
        #pragma unroll
        for (int rt = 0; rt < 2; ++rt) {
            if constexpr (sizeof(TIn) == 4) {
                const float4* p = (const float4*)((const float*)X + (size_t)rowA[rt] * FEAT + k0 + quad * 8);
                float4 f0 = p[0], f1 = p[1];
                half8 h;
                h[0] = (_Float16)f0.x; h[1] = (_Float16)f0.y;
                h[2] = (_Float16)f0.z; h[3] = (_Float16)f0.w;
                h[4] = (_Float16)f1.x; h[5] = (_Float16)f1.y;
                h[6] = (_Float16)f1.z; h[7] = (_Float16)f1.w;
                a[rt] = h;
            } else {
                a[rt] = *(const half8*)((const _Float16*)X + (size_t)rowA[rt] * FEAT + k0 + quad * 8);
            }
        }
        #pragma unroll
        for (int ct = 0; ct < 8; ++ct) {
            half8 b = *(const half8*)&sWt[(ct * 16 + m) * LDW + k0 + quad * 8];
            acc[0][ct] = __builtin_amdgcn_mfma_f32_16x16x32_f16(a[0], b, acc[0][ct], 0, 0, 0);
            acc[1][ct] = __builtin_amdgcn_mfma_f32_16x16x32_f16(a[1], b, acc[1][ct], 0, 0, 0);
        }
    }

    #pragma unroll
    for (int rt = 0; rt < 2; ++rt) {
        int lr0 = wave * 32 + rt * 16 + quad * 4;
        #pragma unroll
        for (int r = 0; r < 4; ++r) {
            int gr = row0 + lr0 + r;
            if (gr < N) {
                float d = dinv[gr];
                #pragma unroll
                for (int ct = 0; ct < 8; ++ct)
                    Y[(size_t)gr * FEAT + ct * 16 + m] = __float2half(d * acc[rt][ct][r]);
            }
        }
    }
}

// ---- per-node aggregation (CSR): 4 rows/gather, fp16 out -------------------
__global__ __launch_bounds__(256) void agg_kernel(const __half* __restrict__ Y,
                                                  const int2* __restrict__ elist,
                                                  const int* __restrict__ offs,
                                                  const int* __restrict__ cnt,
                                                  const float* __restrict__ dinv,
                                                  const float* __restrict__ bias,
                                                  __half* __restrict__ Out, int N) {
    int node = blockIdx.x * 4 + (threadIdx.x >> 6);
    int lane = threadIdx.x & 63;
    if (node >= N) return;
    int grp = lane >> 4;       // replica / edge slot within group-of-4
    int fl  = lane & 15;       // feature block: feats [fl*8, fl*8+8)
    int c = cnt[node];
    const int2* meta = elist + offs[node];

    __half2 z = __floats2half2_rn(0.f, 0.f);
    __half2 a0 = z, a1 = z, a2 = z, a3 = z;
    __half2 b0 = z, b1 = z, b2 = z, b3 = z;

    // self-loop term (weight 1): only replica group 0 contributes it
    if (grp == 0) {
        int4 sv = ((const int4*)(Y + (size_t)node * FEAT))[fl];
        a0 = *(const __half2*)&sv.x; a1 = *(const __half2*)&sv.y;
        a2 = *(const __half2*)&sv.z; a3 = *(const __half2*)&sv.w;
    }

    for (int t = 0; t < c; t += 8) {
        int eA = t + grp;
        int eB = t + 4 + grp;
        int2 mA = (eA < c) ? meta[eA] : make_int2(node, 0);  // w=0 pad, safe row
        int2 mB = (eB < c) ? meta[eB] : make_int2(node, 0);
        int4 vA = *(const int4*)(Y + (size_t)mA.x * FEAT + fl * 8);
        int4 vB = *(const int4*)(Y + (size_t)mB.x * FEAT + fl * 8);
        __half2 wA = *(const __half2*)&mA.y;
        __half2 wB = *(const __half2*)&mB.y;
        a0 = __hfma2(wA, *(const __half2*)&vA.x, a0);
        a1 = __hfma2(wA, *(const __half2*)&vA.y, a1);
        a2 = __hfma2(wA, *(const __half2*)&vA.z, a2);
        a3 = __hfma2(wA, *(const __half2*)&vA.w, a3);
        b0 = __hfma2(wB, *(const __half2*)&vB.x, b0);
        b1 = __hfma2(wB, *(const __half2*)&vB.y, b1);
        b2 = __hfma2(wB, *(const __half2*)&vB.z, b2);
        b3 = __hfma2(wB, *(const __half2*)&vB.w, b3);
    }

    float2 F0 = __half22float2(a0), F1 = __half22float2(a1);
    float2 F2 = __half22float2(a2), F3 = __half22float2(a3);
    {
        float2 t0 = __half22float2(b0), t1 = __half22float2(b1);
        float2 t2 = __half22float2(b2), t3 = __half22float2(b3);
        F0.x += t0.x; F0.y += t0.y; F1.x += t1.x; F1.y += t1.y;
        F2.x += t2.x; F2.y += t2.y; F3.x += t3.x; F3.y += t3.y;
    }
    float f[8] = {F0.x, F0.y, F1.x, F1.y, F2.x, F2.y, F3.x, F3.y};
    #pragma unroll
    for (int i = 0; i < 8; ++i) {
        f[i] += __shfl_xor(f[i], 16);
        f[i] += __shfl_xor(f[i], 32);
    }
    if (grp == 0) {
        float d = dinv[node];
        int c0 = fl * 8;
        float4 bo0 = *(const float4*)(bias + c0);
        float4 bo1 = *(const float4*)(bias + c0 + 4);
        __half2 p01 = __floats2half2_rn(fmaxf(d * f[0] + bo0.x, 0.f), fmaxf(d * f[1] + bo0.y, 0.f));
        __half2 p23 = __floats2half2_rn(fmaxf(d * f[2] + bo0.z, 0.f), fmaxf(d * f[3] + bo0.w, 0.f));
        __half2 p45 = __floats2half2_rn(fmaxf(d * f[4] + bo1.x, 0.f), fmaxf(d * f[5] + bo1.y, 0.f));
        __half2 p67 = __floats2half2_rn(fmaxf(d * f[6] + bo1.z, 0.f), fmaxf(d * f[7] + bo1.w, 0.f));
        iv4 ov = { *(int*)&p01, *(int*)&p23, *(int*)&p45, *(int*)&p67 };
        *(iv4*)(Out + (size_t)node * FEAT + c0) = ov;
    }
}

// ---- pooling (batch sorted): fp16 reads, fp32 accumulate -------------------
__global__ void pool_kernel(const __half* __restrict__ H, const int* __restrict__ batch,
                            float* __restrict__ pooled, int N, int chunk) {
    int f  = threadIdx.x;
    int n0 = blockIdx.x * chunk;
    if (n0 >= N) return;
    int n1 = min(n0 + chunk, N);
    float acc = 0.f;
    int cur = batch[n0];
    for (int n = n0; n < n1; ++n) {
        int g = batch[n];
        if (g != cur) {
            unsafeAtomicAdd(&pooled[cur * FEAT + f], acc);
            acc = 0.f;
            cur = g;
        }
        acc += __half2float(H[(size_t)n * FEAT + f]);
    }
    unsafeAtomicAdd(&pooled[cur * FEAT + f], acc);
}

// ---- classifier ------------------------------------------------------------
__global__ void classify_kernel(const float* __restrict__ pooled, const float* __restrict__ Wc,
                                const float* __restrict__ bc, float* __restrict__ out) {
    int g = blockIdx.x;
    int c = threadIdx.x;
    float acc = bc[c];
    const float* pr = pooled + g * FEAT;
    for (int k = 0; k < FEAT; ++k) acc += pr[k] * Wc[k * OUTC + c];
    out[g * OUTC + c] = 1.0f / (1.0f + expf(-acc));
}

extern "C" void kernel_launch(void* const* d_in, const int* in_sizes, int n_in,
                              void* d_out, int out_size, void* d_ws, size_t ws_size,
                              hipStream_t stream) {
    const float* x     = (const float*)d_in[0];
    const int*   ei    = (const int*)d_in[1];
    const float* ew    = (const float*)d_in[2];
    const int*   batch = (const int*)d_in[3];
    const float* W1    = (const float*)d_in[4];
    const float* b1    = (const float*)d_in[5];
    const float* W2    = (const float*)d_in[6];
    const float* b2    = (const float*)d_in[7];
    const float* Wc    = (const float*)d_in[8];
    const float* bc    = (const float*)d_in[9];
    float* out = (float*)d_out;

    const int N = in_sizes[0] / FEAT;
    const int E = in_sizes[2];
    const int G = out_size / OUTC;
    const int NC = (N + CHUNK - 1) / CHUNK;

    char* w = (char*)d_ws;
    size_t off = 0;
    auto alloc = [&](size_t bytes) {
        void* p = w + off;
        off = (off + bytes + 255) & ~(size_t)255;
        return p;
    };
    int*       deg     = (int*)alloc((size_t)N * 8);      // deg[N] + wsum[N] contiguous
    float*     wsum    = (float*)(deg + N);
    int*       offs    = (int*)alloc((size_t)N * 4);
    int*       cur     = (int*)alloc((size_t)N * 4);
    float*     dinv    = (float*)alloc((size_t)N * 4);
    int*       chunkS  = (int*)alloc((size_t)NC * 4 * 2); // sums + bases
    int*       chunkB  = chunkS + NC;
    int2*      elist   = (int2*)alloc((size_t)E * 8);     // 25.6 MB exact CSR
    __half*    bufY    = (__half*)alloc((size_t)N * FEAT * 2);
    __half*    bufH    = (__half*)alloc((size_t)N * FEAT * 2);
    float*     pooled  = (float*)alloc((size_t)G * FEAT * 4);
    _Float16*  wt1     = (_Float16*)alloc((size_t)FEAT * LDW * 2);
    _Float16*  wt2     = (_Float16*)alloc((size_t)FEAT * LDW * 2);
    (void)ws_size;

    hipMemsetAsync(deg, 0, (size_t)N * 8, stream);
    hipMemsetAsync(pooled, 0, (size_t)G * FEAT * 4, stream);

    k_hist<<<2048, 256, 0, stream>>>(ei, ew, deg, wsum, E);
    wt_prep<<<128, 256, 0, stream>>>(W1, W2, wt1, wt2);
    k_chunksum<<<NC, 512, 0, stream>>>(deg, chunkS, N);
    k_scanchunks<<<1, 64, 0, stream>>>(chunkS, chunkB, NC);
    k_offs<<<NC, 512, 0, stream>>>(deg, wsum, chunkB, offs, cur, dinv, N);
    k_scatter<<<2048, 256, 0, stream>>>(ei, ew, cur, elist, E);

    const int gemm_blocks = (N + 127) / 128;
    const int agg_blocks  = (N + 3) / 4;

    gemm_mfma<float><<<gemm_blocks, 256, 0, stream>>>(x, wt1, dinv, bufY, N);
    agg_kernel<<<agg_blocks, 256, 0, stream>>>(bufY, elist, offs, deg, dinv, b1, bufH, N);
    gemm_mfma<__half><<<gemm_blocks, 256, 0, stream>>>(bufH, wt2, dinv, bufY, N);
    agg_kernel<<<agg_blocks, 256, 0, stream>>>(bufY, elist, offs, deg, dinv, b2, bufH, N);

    const int chunk = 128;
    pool_kernel<<<(N + chunk - 1) / chunk, FEAT, 0, stream>>>(bufH, batch, pooled, N, chunk);
    classify_kernel<<<G, OUTC, 0, stream>>>(pooled, Wc, bc, out);
}

// Round 12
// 494.074 us; speedup vs baseline: 1.9709x; 1.9709x over previous
//
#include <hip/hip_runtime.h>
#include <hip/hip_bf16.h>
#include <hip/hip_fp16.h>

// GCN: h1 = relu(gcn(x,W1,b1)); h2 = relu(gcn(h1,W2,b2));
// pooled = segment_sum(h2, batch); out = sigmoid(pooled@Wc + bc)
// R13/R14 NEUTRAL. R15-17 FAILED: latency-starved bin-sweep; TLP>>locality.
//   BANKED: atomicAdd(float*) = ~200cyc CAS; use unsafeAtomicAdd.
// R18 NEUTRAL. R19: nt hints BACKFIRE. fp16 H GOOD (WRITE 50->25).
// R20 WIN (545->510.7): LDS tile-sort bin_edges, run-coalesced writes.
// R21 (509.0): 512-thr bins -19us; agg 2-way split +17us (less TLP/disp).
// R22 FAILED (974): direct CSR scatter = 8B random stores -> 199MB WRITE
//   (7.8x amplification, 64B sector per store), 288us. BANKED: random
//   fine-grained global writes are ~8x amplified; two-level LDS binning
//   exists to coarsen them. Reverted.
// R23: consolidate measured-best: R20 pipeline + 512-thr bin kernels
//   (R21's verified gain) + UNSPLIT agg (drop R21's verified cost) +
//   merged wt_prep. Pred: agg ~115x2/381MB; total 485-495. Falsif:
//   ~510 => R21 bin-gain attribution wrong, bins pinned at ~145.

#define FEAT 128
#define OUTC 64
#define NB_SHIFT 8
#define BINSZ 256      // nodes per bin
#define CAP 9216       // per-bin edge capacity
#define TILE_A 8192    // edges per phase-A block
#define CNT_STRIDE 16  // binCnt padding: one counter per 64B line
#define LDW 136        // padded W^T row stride (halves)

typedef _Float16 half8 __attribute__((ext_vector_type(8)));
typedef float    f32x4 __attribute__((ext_vector_type(4)));
typedef int      iv4  __attribute__((ext_vector_type(4)));

// ---- Phase A: bin edges by col>>8, LDS tile-sort, run-coalesced writes -----
// 512 threads: halves per-pass iterations; LDS 74KB -> 2 blocks/CU.
__global__ __launch_bounds__(512) void bin_edges(const int* __restrict__ ei,
                                                 const float* __restrict__ ew,
                                                 int* __restrict__ binCnt,
                                                 int2* __restrict__ binned,
                                                 int E, int nbins) {
    extern __shared__ int2 sE[];          // TILE_A entries = 65536 B dynamic
    __shared__ int kh[512], kb[512], kc[512], kg[512], ksc[512];
    int tid = threadIdx.x;
    int e0 = blockIdx.x * TILE_A;
    kh[tid] = 0;
    kc[tid] = 0;
    __syncthreads();
    // pass 1: histogram by bin
    for (int i = 0; i < TILE_A; i += 512) {
        int e = e0 + i + tid;
        if (e < E) atomicAdd(&kh[ei[E + e] >> NB_SHIFT], 1);
    }
    __syncthreads();
    // inclusive scan over 512 (1 elem/thread H-S)
    int v = kh[tid];
    ksc[tid] = v;
    __syncthreads();
    for (int off = 1; off < 512; off <<= 1) {
        int a = (tid >= off) ? ksc[tid - off] : 0;
        __syncthreads();
        ksc[tid] += a;
        __syncthreads();
    }
    kb[tid] = ksc[tid] - v;
    // reserve global bases (one padded counter per bin)
    if (tid < nbins && v > 0) kg[tid] = atomicAdd(&binCnt[tid * CNT_STRIDE], v);
    __syncthreads();
    // pass 2: LDS scatter at sorted position; pack w->half, bin in y high16
    for (int i = 0; i < TILE_A; i += 512) {
        int e = e0 + i + tid;
        if (e < E) {
            int col = ei[E + e];
            int row = ei[e];
            unsigned short hs = __half_as_ushort(__float2half(ew[e]));
            int b = col >> NB_SHIFT;
            int p = kb[b] + atomicAdd(&kc[b], 1);
            int cl = col & (BINSZ - 1);
            sE[p] = make_int2((cl << 24) | row, (b << 16) | (int)hs);
        }
    }
    __syncthreads();
    // pass 3: run-coalesced writeback (consecutive lanes -> consecutive dst)
    int tot = ksc[511];
    for (int i = tid; i < tot; i += 512) {
        int2 m = sE[i];
        int b = ((unsigned)m.y) >> 16;
        int loc = kg[b] + (i - kb[b]);
        if (loc < CAP)
            binned[(size_t)b * CAP + loc] = make_int2(m.x, m.y & 0xFFFF);
    }
}

// ---- Phase B: LDS counting-sort by target cl -> exact CSR, in-place --------
// 512 threads; scan done by tid<256 (BINSZ), passes stride 512.
__global__ __launch_bounds__(512) void bin_sort_csr(int2* __restrict__ binned,
                                                    const int* __restrict__ binCnt,
                                                    int* __restrict__ offs,
                                                    int* __restrict__ cnt,
                                                    float* __restrict__ dinv, int N) {
    extern __shared__ int2 sE[];          // CAP entries = 73728 B dynamic
    __shared__ float dsum[BINSZ];
    __shared__ int kh[BINSZ], kb[BINSZ], ksc[BINSZ];
    int tid = threadIdx.x, b = blockIdx.x;
    int node0 = b << NB_SHIFT;
    if (tid < BINSZ) { dsum[tid] = 0.f; kh[tid] = 0; }
    __syncthreads();
    int ne = min(binCnt[b * CNT_STRIDE], CAP);
    int2* src = binned + (size_t)b * CAP;
    // pass 1: per-target histogram + weighted degree (w is half in y low16)
    for (int i = tid; i < ne; i += 512) {
        int2 m = src[i];
        int cl = ((unsigned)m.x) >> 24;
        atomicAdd(&kh[cl], 1);
        unsafeAtomicAdd(&dsum[cl], __half2float(__ushort_as_half((unsigned short)(m.y & 0xFFFF))));
    }
    __syncthreads();
    // exclusive scan over 256 (threads < 256 participate)
    int v = 0;
    if (tid < BINSZ) { v = kh[tid]; ksc[tid] = v; }
    __syncthreads();
    for (int off = 1; off < BINSZ; off <<= 1) {
        int t = (tid < BINSZ && tid >= off) ? ksc[tid - off] : 0;
        __syncthreads();
        if (tid < BINSZ) ksc[tid] += t;
        __syncthreads();
    }
    if (tid < BINSZ) { kb[tid] = ksc[tid] - v; kh[tid] = 0; }
    __syncthreads();
    // pass 2: scatter into LDS at sorted position; duplicate half w -> half2
    for (int i = tid; i < ne; i += 512) {
        int2 m = src[i];
        int cl = ((unsigned)m.x) >> 24;
        int p = kb[cl] + atomicAdd(&kh[cl], 1);
        int hw = m.y & 0xFFFF;
        sE[p] = make_int2(m.x & 0xFFFFFF, hw | (hw << 16));
    }
    __syncthreads();
    // pass 3: sequential coalesced write-back, in place
    for (int i = tid; i < ne; i += 512) src[i] = sE[i];
    int node = node0 + tid;
    if (tid < BINSZ && node < N) {
        offs[node] = b * CAP + kb[tid];
        cnt[node]  = kh[tid];
        dinv[node] = rsqrtf(1.0f + dsum[tid]);
    }
}

// ---- one-time padded W^T fp16 prep for BOTH layers (row stride LDW) --------
__global__ void wt_prep(const float* __restrict__ W1, const float* __restrict__ W2,
                        _Float16* __restrict__ Wt1, _Float16* __restrict__ Wt2) {
    int i = blockIdx.x * 256 + threadIdx.x;   // i < 32768
    int sel = i >> 14;
    int r = i & 16383;
    int n = r >> 7, k = r & 127;
    const float* W = sel ? W2 : W1;
    _Float16* Wt = sel ? Wt2 : Wt1;
    Wt[(size_t)n * LDW + k] = (_Float16)W[(size_t)k * FEAT + n];
}

// ---- Y(fp16) = dinv[:,None]*(X @ W) via MFMA; TIn = float or __half --------
template<typename TIn>
__global__ __launch_bounds__(256) void gemm_mfma(const TIn* __restrict__ X,
                                                 const _Float16* __restrict__ Wt,
                                                 const float* __restrict__ dinv,
                                                 __half* __restrict__ Y, int N) {
    __shared__ _Float16 sWt[FEAT * LDW];   // 34816 B
    int tid  = threadIdx.x;
    int row0 = blockIdx.x * 128;
    {
        const int4* src = (const int4*)Wt;
        int4* dst = (int4*)sWt;
        for (int i = tid; i < (FEAT * LDW) / 8; i += 256) dst[i] = src[i];
    }
    __syncthreads();

    int wave = tid >> 6;
    int lane = tid & 63;
    int m    = lane & 15;
    int quad = lane >> 4;

    f32x4 acc[2][8];
    #pragma unroll
    for (int rt = 0; rt < 2; ++rt)
        #pragma unroll
        for (int ct = 0; ct < 8; ++ct)
            acc[rt][ct] = (f32x4){0.f, 0.f, 0.f, 0.f};

    int rowA[2];
    rowA[0] = min(row0 + wave * 32 + m, N - 1);
    rowA[1] = min(row0 + wave * 32 + 16 + m, N - 1);

    #pragma unroll
    for (int kt = 0; kt < 4; ++kt) {
        int k0 = kt * 32;
        half8 a[2];
        #pragma unroll
        for (int rt = 0; rt < 2; ++rt) {
            if constexpr (sizeof(TIn) == 4) {
                const float4* p = (const float4*)((const float*)X + (size_t)rowA[rt] * FEAT + k0 + quad * 8);
                float4 f0 = p[0], f1 = p[1];
                half8 h;
                h[0] = (_Float16)f0.x; h[1] = (_Float16)f0.y;
                h[2] = (_Float16)f0.z; h[3] = (_Float16)f0.w;
                h[4] = (_Float16)f1.x; h[5] = (_Float16)f1.y;
                h[6] = (_Float16)f1.z; h[7] = (_Float16)f1.w;
                a[rt] = h;
            } else {
                a[rt] = *(const half8*)((const _Float16*)X + (size_t)rowA[rt] * FEAT + k0 + quad * 8);
            }
        }
        #pragma unroll
        for (int ct = 0; ct < 8; ++ct) {
            half8 b = *(const half8*)&sWt[(ct * 16 + m) * LDW + k0 + quad * 8];
            acc[0][ct] = __builtin_amdgcn_mfma_f32_16x16x32_f16(a[0], b, acc[0][ct], 0, 0, 0);
            acc[1][ct] = __builtin_amdgcn_mfma_f32_16x16x32_f16(a[1], b, acc[1][ct], 0, 0, 0);
        }
    }

    #pragma unroll
    for (int rt = 0; rt < 2; ++rt) {
        int lr0 = wave * 32 + rt * 16 + quad * 4;
        #pragma unroll
        for (int r = 0; r < 4; ++r) {
            int gr = row0 + lr0 + r;
            if (gr < N) {
                float d = dinv[gr];
                #pragma unroll
                for (int ct = 0; ct < 8; ++ct)
                    Y[(size_t)gr * FEAT + ct * 16 + m] = __float2half(d * acc[rt][ct][r]);
            }
        }
    }
}

// ---- per-node aggregation (CSR): 4 rows/gather, fp16 out -------------------
__global__ __launch_bounds__(256) void agg_kernel(const __half* __restrict__ Y,
                                                  const int2* __restrict__ elist,
                                                  const int* __restrict__ offs,
                                                  const int* __restrict__ cnt,
                                                  const float* __restrict__ dinv,
                                                  const float* __restrict__ bias,
                                                  __half* __restrict__ Out, int N) {
    int node = blockIdx.x * 4 + (threadIdx.x >> 6);
    int lane = threadIdx.x & 63;
    if (node >= N) return;
    int grp = lane >> 4;       // replica / edge slot within group-of-4
    int fl  = lane & 15;       // feature block: feats [fl*8, fl*8+8)
    int c = cnt[node];
    const int2* meta = elist + offs[node];

    __half2 z = __floats2half2_rn(0.f, 0.f);
    __half2 a0 = z, a1 = z, a2 = z, a3 = z;
    __half2 b0 = z, b1 = z, b2 = z, b3 = z;

    // self-loop term (weight 1): only replica group 0 contributes it
    if (grp == 0) {
        int4 sv = ((const int4*)(Y + (size_t)node * FEAT))[fl];
        a0 = *(const __half2*)&sv.x; a1 = *(const __half2*)&sv.y;
        a2 = *(const __half2*)&sv.z; a3 = *(const __half2*)&sv.w;
    }

    for (int t = 0; t < c; t += 8) {
        int eA = t + grp;
        int eB = t + 4 + grp;
        int2 mA = (eA < c) ? meta[eA] : make_int2(node, 0);  // w=0 pad, safe row
        int2 mB = (eB < c) ? meta[eB] : make_int2(node, 0);
        int4 vA = *(const int4*)(Y + (size_t)mA.x * FEAT + fl * 8);
        int4 vB = *(const int4*)(Y + (size_t)mB.x * FEAT + fl * 8);
        __half2 wA = *(const __half2*)&mA.y;
        __half2 wB = *(const __half2*)&mB.y;
        a0 = __hfma2(wA, *(const __half2*)&vA.x, a0);
        a1 = __hfma2(wA, *(const __half2*)&vA.y, a1);
        a2 = __hfma2(wA, *(const __half2*)&vA.z, a2);
        a3 = __hfma2(wA, *(const __half2*)&vA.w, a3);
        b0 = __hfma2(wB, *(const __half2*)&vB.x, b0);
        b1 = __hfma2(wB, *(const __half2*)&vB.y, b1);
        b2 = __hfma2(wB, *(const __half2*)&vB.z, b2);
        b3 = __hfma2(wB, *(const __half2*)&vB.w, b3);
    }

    float2 F0 = __half22float2(a0), F1 = __half22float2(a1);
    float2 F2 = __half22float2(a2), F3 = __half22float2(a3);
    {
        float2 t0 = __half22float2(b0), t1 = __half22float2(b1);
        float2 t2 = __half22float2(b2), t3 = __half22float2(b3);
        F0.x += t0.x; F0.y += t0.y; F1.x += t1.x; F1.y += t1.y;
        F2.x += t2.x; F2.y += t2.y; F3.x += t3.x; F3.y += t3.y;
    }
    float f[8] = {F0.x, F0.y, F1.x, F1.y, F2.x, F2.y, F3.x, F3.y};
    #pragma unroll
    for (int i = 0; i < 8; ++i) {
        f[i] += __shfl_xor(f[i], 16);
        f[i] += __shfl_xor(f[i], 32);
    }
    if (grp == 0) {
        float d = dinv[node];
        int c0 = fl * 8;
        float4 bo0 = *(const float4*)(bias + c0);
        float4 bo1 = *(const float4*)(bias + c0 + 4);
        __half2 p01 = __floats2half2_rn(fmaxf(d * f[0] + bo0.x, 0.f), fmaxf(d * f[1] + bo0.y, 0.f));
        __half2 p23 = __floats2half2_rn(fmaxf(d * f[2] + bo0.z, 0.f), fmaxf(d * f[3] + bo0.w, 0.f));
        __half2 p45 = __floats2half2_rn(fmaxf(d * f[4] + bo1.x, 0.f), fmaxf(d * f[5] + bo1.y, 0.f));
        __half2 p67 = __floats2half2_rn(fmaxf(d * f[6] + bo1.z, 0.f), fmaxf(d * f[7] + bo1.w, 0.f));
        iv4 ov = { *(int*)&p01, *(int*)&p23, *(int*)&p45, *(int*)&p67 };
        *(iv4*)(Out + (size_t)node * FEAT + c0) = ov;
    }
}

// ---- pooling (batch sorted): fp16 reads, fp32 accumulate -------------------
__global__ void pool_kernel(const __half* __restrict__ H, const int* __restrict__ batch,
                            float* __restrict__ pooled, int N, int chunk) {
    int f  = threadIdx.x;
    int n0 = blockIdx.x * chunk;
    if (n0 >= N) return;
    int n1 = min(n0 + chunk, N);
    float acc = 0.f;
    int cur = batch[n0];
    for (int n = n0; n < n1; ++n) {
        int g = batch[n];
        if (g != cur) {
            unsafeAtomicAdd(&pooled[cur * FEAT + f], acc);
            acc = 0.f;
            cur = g;
        }
        acc += __half2float(H[(size_t)n * FEAT + f]);
    }
    unsafeAtomicAdd(&pooled[cur * FEAT + f], acc);
}

// ---- classifier ------------------------------------------------------------
__global__ void classify_kernel(const float* __restrict__ pooled, const float* __restrict__ Wc,
                                const float* __restrict__ bc, float* __restrict__ out) {
    int g = blockIdx.x;
    int c = threadIdx.x;
    float acc = bc[c];
    const float* pr = pooled + g * FEAT;
    for (int k = 0; k < FEAT; ++k) acc += pr[k] * Wc[k * OUTC + c];
    out[g * OUTC + c] = 1.0f / (1.0f + expf(-acc));
}

extern "C" void kernel_launch(void* const* d_in, const int* in_sizes, int n_in,
                              void* d_out, int out_size, void* d_ws, size_t ws_size,
                              hipStream_t stream) {
    const float* x     = (const float*)d_in[0];
    const int*   ei    = (const int*)d_in[1];
    const float* ew    = (const float*)d_in[2];
    const int*   batch = (const int*)d_in[3];
    const float* W1    = (const float*)d_in[4];
    const float* b1    = (const float*)d_in[5];
    const float* W2    = (const float*)d_in[6];
    const float* b2    = (const float*)d_in[7];
    const float* Wc    = (const float*)d_in[8];
    const float* bc    = (const float*)d_in[9];
    float* out = (float*)d_out;

    const int N = in_sizes[0] / FEAT;
    const int E = in_sizes[2];
    const int G = out_size / OUTC;
    const int nbins = (N + BINSZ - 1) / BINSZ;

    char* w = (char*)d_ws;
    size_t off = 0;
    auto alloc = [&](size_t bytes) {
        void* p = w + off;
        off = (off + bytes + 255) & ~(size_t)255;
        return p;
    };
    float*     dinv   = (float*)alloc((size_t)N * 4);
    int*       cnt    = (int*)alloc((size_t)N * 4);
    int*       offs   = (int*)alloc((size_t)N * 4);
    int*       binCnt = (int*)alloc((size_t)nbins * CNT_STRIDE * 4);  // line-padded
    int2*      binned = (int2*)alloc((size_t)nbins * CAP * 8);  // ~28.8 MB (sorted in place)
    __half*    bufY   = (__half*)alloc((size_t)N * FEAT * 2);   // fp16 Y
    __half*    bufH   = (__half*)alloc((size_t)N * FEAT * 2);   // fp16 h
    float*     pooled = (float*)alloc((size_t)G * FEAT * 4);
    _Float16*  wt1    = (_Float16*)alloc((size_t)FEAT * LDW * 2);
    _Float16*  wt2    = (_Float16*)alloc((size_t)FEAT * LDW * 2);
    (void)ws_size;

    hipMemsetAsync(binCnt, 0, (size_t)nbins * CNT_STRIDE * 4, stream);
    hipMemsetAsync(pooled, 0, (size_t)G * FEAT * 4, stream);

    bin_edges<<<(E + TILE_A - 1) / TILE_A, 512, (size_t)TILE_A * sizeof(int2), stream>>>(ei, ew, binCnt, binned, E, nbins);
    bin_sort_csr<<<nbins, 512, (size_t)CAP * sizeof(int2), stream>>>(binned, binCnt, offs, cnt, dinv, N);
    wt_prep<<<128, 256, 0, stream>>>(W1, W2, wt1, wt2);

    const int gemm_blocks = (N + 127) / 128;
    const int agg_blocks  = (N + 3) / 4;

    gemm_mfma<float><<<gemm_blocks, 256, 0, stream>>>(x, wt1, dinv, bufY, N);
    agg_kernel<<<agg_blocks, 256, 0, stream>>>(bufY, binned, offs, cnt, dinv, b1, bufH, N);
    gemm_mfma<__half><<<gemm_blocks, 256, 0, stream>>>(bufH, wt2, dinv, bufY, N);
    agg_kernel<<<agg_blocks, 256, 0, stream>>>(bufY, binned, offs, cnt, dinv, b2, bufH, N);

    const int chunk = 128;
    pool_kernel<<<(N + chunk - 1) / chunk, FEAT, 0, stream>>>(bufH, batch, pooled, N, chunk);
    classify_kernel<<<G, OUTC, 0, stream>>>(pooled, Wc, bc, out);
}